// Round 2
// baseline (3403.999 us; speedup 1.0000x reference)
//
#include <hip/hip_runtime.h>
#include <hip/hip_bf16.h>
#include <hip/hip_fp16.h>

#define BT 16384
#define F 32
#define H 256
#define FH 8192

typedef _Float16 half8 __attribute__((ext_vector_type(8)));
typedef float float4v __attribute__((ext_vector_type(4)));

// ---------------------------------------------------------------------------
// Prep: transpose w2/wg/wf (F,H_contr,H_out) fp32 -> [f][n_out][h_contr] fp16
// ---------------------------------------------------------------------------
__global__ __launch_bounds__(256) void transpose_w_kernel(
    const float* __restrict__ w2, const float* __restrict__ wg,
    const float* __restrict__ wf, _Float16* __restrict__ wt)
{
    __shared__ float tile[64][65];
    int bid = blockIdx.x;
    int tens = bid >> 9, rem = bid & 511;
    int f = rem >> 4, tl = rem & 15;
    int hb = (tl >> 2) * 64, nb = (tl & 3) * 64;
    const float* src = (tens == 0 ? w2 : (tens == 1 ? wg : wf)) + f * 65536;
    _Float16* dst = wt + (size_t)tens * 2097152 + f * 65536;
    int lane = threadIdx.x & 63, w = threadIdx.x >> 6;
    for (int i = 0; i < 16; ++i) {
        int r = i * 4 + w;
        tile[r][lane] = src[(hb + r) * 256 + nb + lane];
    }
    __syncthreads();
    for (int i = 0; i < 16; ++i) {
        int c = i * 4 + w;
        dst[(nb + c) * 256 + hb + lane] = (_Float16)tile[lane][c];
    }
}

// ---------------------------------------------------------------------------
// Prep: Wcat[n][k] fp16, n<256 from sw1 (8192,256), n in [256,288) from ssw
// ---------------------------------------------------------------------------
__global__ __launch_bounds__(256) void transpose_s_kernel(
    const float* __restrict__ sw1, const float* __restrict__ ssw,
    _Float16* __restrict__ wcat)
{
    __shared__ float tile[64][65];
    int bid = blockIdx.x;
    int lane = threadIdx.x & 63, w = threadIdx.x >> 6;
    if (bid < 512) {
        int k0 = (bid >> 2) * 64, n0 = (bid & 3) * 64;
        for (int i = 0; i < 16; ++i) {
            int r = i * 4 + w;
            tile[r][lane] = sw1[(size_t)(k0 + r) * 256 + n0 + lane];
        }
        __syncthreads();
        for (int i = 0; i < 16; ++i) {
            int c = i * 4 + w;
            wcat[(size_t)(n0 + c) * FH + k0 + lane] = (_Float16)tile[lane][c];
        }
    } else {
        int k0 = (bid - 512) * 64;
        int t = threadIdx.x;
        for (int i = 0; i < 8; ++i) {
            int idx = t + i * 256;
            int r = idx >> 5, cc = idx & 31;
            tile[r][cc] = ssw[(size_t)(k0 + r) * 32 + cc];
        }
        __syncthreads();
        for (int i = 0; i < 8; ++i) {
            int idx = t + i * 256;
            int c = idx >> 6, rr = idx & 63;
            wcat[(size_t)(256 + c) * FH + k0 + rr] = (_Float16)tile[rr][c];
        }
    }
}

// ---------------------------------------------------------------------------
// Fused per-feature GRN: 3 GEMMs (K=256) + GLU + residual + LayerNorm
// One block = 32 tokens x one feature f. stacked written fp16 (chunk-local).
// MFMA 16x16x32 f16: A[m=ln][k=q*8+j], B[k=q*8+j][n=ln], C row=q*4+r col=ln
// ---------------------------------------------------------------------------
__device__ __forceinline__ void gemm_stage(
    const _Float16* __restrict__ Bsrc,   // weight slice for this f: [n][k], k contig
    const _Float16* As, _Float16* Bs,
    int t, int wv, int ln, int q, float4v acc[2][4])
{
    for (int kc = 0; kc < 4; ++kc) {
        __syncthreads();
        for (int v = t; v < 2048; v += 256) {
            int n = v >> 3, kv = (v & 7) * 8;
            *(int4*)&Bs[n * 72 + kv] = *(const int4*)&Bsrc[n * 256 + kc * 64 + kv];
        }
        __syncthreads();
        for (int ks = 0; ks < 2; ++ks) {
            int kb = kc * 64 + ks * 32 + q * 8;
            half8 a0 = *(const half8*)&As[(0 + ln) * 264 + kb];
            half8 a1 = *(const half8*)&As[(16 + ln) * 264 + kb];
#pragma unroll
            for (int nt = 0; nt < 4; ++nt) {
                half8 b8 = *(const half8*)&Bs[(wv * 64 + nt * 16 + ln) * 72 + ks * 32 + q * 8];
                acc[0][nt] = __builtin_amdgcn_mfma_f32_16x16x32_f16(a0, b8, acc[0][nt], 0, 0, 0);
                acc[1][nt] = __builtin_amdgcn_mfma_f32_16x16x32_f16(a1, b8, acc[1][nt], 0, 0, 0);
            }
        }
    }
}

__global__ __launch_bounds__(256) void grn_kernel(
    const float* __restrict__ x, const float* __restrict__ w1, const float* __restrict__ b1,
    const float* __restrict__ b2, const float* __restrict__ bg, const float* __restrict__ bfv_,
    const float* __restrict__ gamma, const float* __restrict__ beta,
    const float* __restrict__ wsk, const float* __restrict__ bsk,
    const _Float16* __restrict__ w2t, const _Float16* __restrict__ wgt,
    const _Float16* __restrict__ wft, _Float16* __restrict__ stacked, int tok_base)
{
    __shared__ __align__(16) char smem[53888];
    _Float16* As = (_Float16*)smem;                     // 32 x 264 fp16
    float* xs = (float*)(smem + 16896);                 // 32
    _Float16* Bs = (_Float16*)(smem + 17024);           // 256 x 72 fp16
    float* ys = (float*)(smem + 17024);                 // 32 x 265 f32 (alias Bs)
    float* red = (float*)(smem + 17024 + 33920);        // 512
    float* mv = (float*)(smem + 17024 + 33920 + 2048);  // 64

    const int f = blockIdx.y;
    const int tok0 = blockIdx.x * 32;                   // chunk-local
    const int t = threadIdx.x;
    const int wv = t >> 6;
    const int ln = t & 15;
    const int q = (t & 63) >> 4;

    if (t < 32) xs[t] = x[(size_t)(tok_base + tok0 + t) * F + f];
    __syncthreads();

    // A = elu(x * w1 + b1), fp16 into LDS (32 x 256, stride 264)
    {
        float w1v = w1[f * H + t];
        float b1v = b1[f * H + t];
#pragma unroll 4
        for (int i = 0; i < 32; ++i) {
            float z = xs[i] * w1v + b1v;
            float e = z > 0.f ? z : (expf(z) - 1.f);
            As[i * 264 + t] = (_Float16)e;
        }
    }
    // stage 1: h2 = A @ w2 + b2
    float4v acc1[2][4];
#pragma unroll
    for (int mt = 0; mt < 2; ++mt)
#pragma unroll
        for (int nt = 0; nt < 4; ++nt)
#pragma unroll
            for (int r = 0; r < 4; ++r) acc1[mt][nt][r] = 0.f;
    gemm_stage(w2t + (size_t)f * 65536, As, Bs, t, wv, ln, q, acc1);

    __syncthreads();  // all stage-1 MFMA reads of As done
    {
        const float* b2f = b2 + f * H;
#pragma unroll
        for (int mt = 0; mt < 2; ++mt)
#pragma unroll
            for (int nt = 0; nt < 4; ++nt) {
                int n = wv * 64 + nt * 16 + ln;
                float b2v = b2f[n];
#pragma unroll
                for (int r = 0; r < 4; ++r) {
                    int m = mt * 16 + q * 4 + r;
                    As[m * 264 + n] = (_Float16)(acc1[mt][nt][r] + b2v);
                }
            }
    }
    // stage 2: Cg = h2 @ wg, Cf = h2 @ wf (sequential, reuse Bs)
    float4v accG[2][4], accF[2][4];
#pragma unroll
    for (int mt = 0; mt < 2; ++mt)
#pragma unroll
        for (int nt = 0; nt < 4; ++nt)
#pragma unroll
            for (int r = 0; r < 4; ++r) { accG[mt][nt][r] = 0.f; accF[mt][nt][r] = 0.f; }
    gemm_stage(wgt + (size_t)f * 65536, As, Bs, t, wv, ln, q, accG);
    gemm_stage(wft + (size_t)f * 65536, As, Bs, t, wv, ln, q, accF);

    // epilogue: y = sigmoid(Cg+bg)*(Cf+bf) + x*ws + bs, into LDS f32
    __syncthreads();
    {
        const float* bgf = bg + f * H;
        const float* bff = bfv_ + f * H;
        const float* wsf = wsk + f * H;
        const float* bsf = bsk + f * H;
#pragma unroll
        for (int mt = 0; mt < 2; ++mt)
#pragma unroll
            for (int nt = 0; nt < 4; ++nt) {
                int n = wv * 64 + nt * 16 + ln;
                float bgv = bgf[n], bfv = bff[n], wsv = wsf[n], bsv = bsf[n];
#pragma unroll
                for (int r = 0; r < 4; ++r) {
                    int m = mt * 16 + q * 4 + r;
                    float cg = accG[mt][nt][r] + bgv;
                    float cf = accF[mt][nt][r] + bfv;
                    float sig = 1.f / (1.f + expf(-cg));
                    ys[m * 265 + n] = sig * cf + xs[m] * wsv + bsv;
                }
            }
    }
    __syncthreads();
    // LayerNorm over H=256 per row
    {
        int row = t >> 3, seg = t & 7;
        float s1 = 0.f, s2 = 0.f;
#pragma unroll 8
        for (int j = 0; j < 32; ++j) {
            float v = ys[row * 265 + seg * 32 + j];
            s1 += v; s2 += v * v;
        }
        red[t] = s1; red[256 + t] = s2;
    }
    __syncthreads();
    if (t < 32) {
        float a = 0.f, b = 0.f;
        for (int s = 0; s < 8; ++s) { a += red[t * 8 + s]; b += red[256 + t * 8 + s]; }
        float mean = a * (1.f / 256.f);
        float var = b * (1.f / 256.f) - mean * mean;
        mv[t] = mean;
        mv[32 + t] = rsqrtf(var + 1e-5f);
    }
    __syncthreads();
    {
        float gv = gamma[f * H + t], bv = beta[f * H + t];
        for (int i = 0; i < 32; ++i) {
            float v = (ys[i * 265 + t] - mv[i]) * mv[32 + i] * gv + bv;
            stacked[(size_t)(tok0 + i) * FH + f * H + t] = (_Float16)v;
        }
    }
}

// ---------------------------------------------------------------------------
// Selection GEMM: M=C tokens (chunk-local), K=8192, N=288 (sw1 || ssw)
// block = 64 tokens; wave wv owns n-tiles {wv, wv+4, ...} (5,5,4,4)
// ---------------------------------------------------------------------------
__global__ __launch_bounds__(256) void sel_gemm_kernel(
    const _Float16* __restrict__ stacked, const _Float16* __restrict__ wcat,
    const float* __restrict__ sb1, const float* __restrict__ ssb,
    float* __restrict__ sh_pre, float* __restrict__ sres)
{
    __shared__ __align__(16) _Float16 As2[64 * 72];
    __shared__ __align__(16) _Float16 Bs2[288 * 72];
    const int t = threadIdx.x;
    const int wv = t >> 6, ln = t & 15, q = (t & 63) >> 4;
    const int tok0 = blockIdx.x * 64;                   // chunk-local
    const int NT = (wv < 2) ? 5 : 4;
    float4v acc[4][5];
#pragma unroll
    for (int mt = 0; mt < 4; ++mt)
#pragma unroll
        for (int i = 0; i < 5; ++i)
#pragma unroll
            for (int r = 0; r < 4; ++r) acc[mt][i][r] = 0.f;

    for (int kc = 0; kc < 128; ++kc) {
        __syncthreads();
        {
            const _Float16* srcA = stacked + (size_t)tok0 * FH + kc * 64;
#pragma unroll
            for (int i = 0; i < 2; ++i) {
                int v = t + i * 256;
                int row = v >> 3, kv = (v & 7) * 8;
                *(int4*)&As2[row * 72 + kv] = *(const int4*)&srcA[(size_t)row * FH + kv];
            }
            const _Float16* srcB = wcat + kc * 64;
#pragma unroll
            for (int i = 0; i < 9; ++i) {
                int v = t + i * 256;
                int n = v >> 3, kv = (v & 7) * 8;
                *(int4*)&Bs2[n * 72 + kv] = *(const int4*)&srcB[(size_t)n * FH + kv];
            }
        }
        __syncthreads();
        for (int ks = 0; ks < 2; ++ks) {
            half8 af[4];
#pragma unroll
            for (int mt = 0; mt < 4; ++mt)
                af[mt] = *(const half8*)&As2[(mt * 16 + ln) * 72 + ks * 32 + q * 8];
            for (int i = 0; i < NT; ++i) {
                int ntg = wv + 4 * i;
                half8 b8 = *(const half8*)&Bs2[(ntg * 16 + ln) * 72 + ks * 32 + q * 8];
#pragma unroll
                for (int mt = 0; mt < 4; ++mt)
                    acc[mt][i] = __builtin_amdgcn_mfma_f32_16x16x32_f16(af[mt], b8, acc[mt][i], 0, 0, 0);
            }
        }
    }
    for (int i = 0; i < NT; ++i) {
        int n = (wv + 4 * i) * 16 + ln;
        if (n < 256) {
            float bv = sb1[n];
#pragma unroll
            for (int mt = 0; mt < 4; ++mt)
#pragma unroll
                for (int r = 0; r < 4; ++r) {
                    int m = tok0 + mt * 16 + q * 4 + r;
                    sh_pre[(size_t)m * 256 + n] = acc[mt][i][r] + bv;
                }
        } else {
            float bv = ssb[n - 256];
#pragma unroll
            for (int mt = 0; mt < 4; ++mt)
#pragma unroll
                for (int r = 0; r < 4; ++r) {
                    int m = tok0 + mt * 16 + q * 4 + r;
                    sres[(size_t)m * 32 + (n - 256)] = acc[mt][i][r] + bv;
                }
        }
    }
}

// ---------------------------------------------------------------------------
// Selection tail: elu -> fc2(256->32) -> GLU(32x32) -> LN -> softmax
// block = 16 tokens (chunk-local)
// ---------------------------------------------------------------------------
__global__ __launch_bounds__(256) void sel_tail_kernel(
    const float* __restrict__ sh_pre, const float* __restrict__ sres,
    const float* __restrict__ sw2, const float* __restrict__ sb2,
    const float* __restrict__ swg, const float* __restrict__ sbg,
    const float* __restrict__ swf, const float* __restrict__ sbf,
    const float* __restrict__ sgam, const float* __restrict__ sbet,
    float* __restrict__ wts)
{
    __shared__ float sw2s[256 * 32];
    __shared__ float swgs[32 * 32], swfs[32 * 32];
    __shared__ float sb2s[32], sbgs[32], sbfs[32], sgams[32], sbets[32];
    __shared__ float shv[256], red[256], tv[32], sv[32], misc[4];
    const int t = threadIdx.x;
    for (int i = 0; i < 32; ++i) sw2s[t + i * 256] = sw2[t + i * 256];
    for (int i = 0; i < 4; ++i) {
        swgs[t + i * 256] = swg[t + i * 256];
        swfs[t + i * 256] = swf[t + i * 256];
    }
    if (t < 32) {
        sb2s[t] = sb2[t]; sbgs[t] = sbg[t]; sbfs[t] = sbf[t];
        sgams[t] = sgam[t]; sbets[t] = sbet[t];
    }
    __syncthreads();
    const int tok0 = blockIdx.x * 16;
    for (int tk = 0; tk < 16; ++tk) {
        int token = tok0 + tk;
        {
            float z = sh_pre[(size_t)token * 256 + t];
            shv[t] = z > 0.f ? z : (expf(z) - 1.f);
        }
        __syncthreads();
        {
            int j = t & 31, kk = t >> 5;
            float p = 0.f;
#pragma unroll 8
            for (int i2 = 0; i2 < 32; ++i2) {
                int k = kk * 32 + i2;
                p += shv[k] * sw2s[k * 32 + j];
            }
            red[t] = p;
        }
        __syncthreads();
        if (t < 32) {
            float a = sb2s[t];
            for (int kk = 0; kk < 8; ++kk) a += red[kk * 32 + t];
            tv[t] = a;
        }
        __syncthreads();
        if (t < 32) {
            float g = sbgs[t], u = sbfs[t];
            for (int i2 = 0; i2 < 32; ++i2) {
                float tvv = tv[i2];
                g += tvv * swgs[i2 * 32 + t];
                u += tvv * swfs[i2 * 32 + t];
            }
            float sig = 1.f / (1.f + expf(-g));
            sv[t] = sres[(size_t)token * 32 + t] + sig * u;
        }
        __syncthreads();
        if (t == 0) {
            float a = 0.f, b = 0.f;
            for (int j = 0; j < 32; ++j) { float v = sv[j]; a += v; b += v * v; }
            float mean = a / 32.f, var = b / 32.f - mean * mean;
            misc[0] = mean; misc[1] = rsqrtf(var + 1e-5f);
        }
        __syncthreads();
        if (t < 32) sv[t] = (sv[t] - misc[0]) * misc[1] * sgams[t] + sbets[t];
        __syncthreads();
        if (t == 0) {
            float mx = -1e30f;
            for (int j = 0; j < 32; ++j) mx = fmaxf(mx, sv[j]);
            misc[2] = mx;
        }
        __syncthreads();
        if (t < 32) sv[t] = expf(sv[t] - misc[2]);
        __syncthreads();
        if (t == 0) {
            float s = 0.f;
            for (int j = 0; j < 32; ++j) s += sv[j];
            misc[3] = 1.f / s;
        }
        __syncthreads();
        if (t < 32) wts[(size_t)token * 32 + t] = sv[t] * misc[3];
        __syncthreads();
    }
}

// ---------------------------------------------------------------------------
// out[tok_base+token][h] = sum_f stacked[token][f][h] * w[token][f]
// ---------------------------------------------------------------------------
__global__ __launch_bounds__(256) void wsum_kernel(
    const _Float16* __restrict__ stacked, const float* __restrict__ wts,
    float* __restrict__ out, int tok_base)
{
    int token = blockIdx.x;                              // chunk-local
    int t = threadIdx.x;
    const _Float16* sp = stacked + (size_t)token * FH;
    const float* wp = wts + (size_t)token * 32;
    float a = 0.f;
#pragma unroll
    for (int f = 0; f < 32; ++f) a += (float)sp[f * 256 + t] * wp[f];
    out[(size_t)(tok_base + token) * 256 + t] = a;
}

// ---------------------------------------------------------------------------
extern "C" void kernel_launch(void* const* d_in, const int* in_sizes, int n_in,
                              void* d_out, int out_size, void* d_ws, size_t ws_size,
                              hipStream_t stream)
{
    (void)in_sizes; (void)n_in; (void)out_size;
    const float* x    = (const float*)d_in[0];
    const float* w1   = (const float*)d_in[1];
    const float* b1   = (const float*)d_in[2];
    const float* w2   = (const float*)d_in[3];
    const float* b2   = (const float*)d_in[4];
    const float* wg   = (const float*)d_in[5];
    const float* bg   = (const float*)d_in[6];
    const float* wf   = (const float*)d_in[7];
    const float* bfp  = (const float*)d_in[8];
    const float* gamma= (const float*)d_in[9];
    const float* beta = (const float*)d_in[10];
    const float* wsk  = (const float*)d_in[11];
    const float* bsk  = (const float*)d_in[12];
    const float* sw1  = (const float*)d_in[13];
    const float* sb1  = (const float*)d_in[14];
    const float* sw2  = (const float*)d_in[15];
    const float* sb2  = (const float*)d_in[16];
    const float* swg  = (const float*)d_in[17];
    const float* sbg  = (const float*)d_in[18];
    const float* swf  = (const float*)d_in[19];
    const float* sbf  = (const float*)d_in[20];
    const float* sgam = (const float*)d_in[21];
    const float* sbet = (const float*)d_in[22];
    const float* ssw  = (const float*)d_in[23];
    const float* ssb  = (const float*)d_in[24];

    // ---- workspace layout, chunk size adaptive to ws_size ----
    const size_t fixedB = 12582912 + 4718592;            // wt (12 MiB) + wcat (4.5 MiB)
    int C = BT;                                          // tokens per chunk
    while (C > 512) {
        size_t need = fixedB + (size_t)C * 17664;        // stacked+sh_pre+sres+wts per token
        if (need <= ws_size) break;
        C >>= 1;
    }
    const int nChunks = BT / C;

    char* ws = (char*)d_ws;
    _Float16* wt      = (_Float16*)ws;                                   // 3 x 2,097,152 fp16
    _Float16* wcat    = (_Float16*)(ws + 12582912);                      // 288 x 8192 fp16
    char* p = ws + fixedB;
    _Float16* stacked = (_Float16*)p;            p += (size_t)C * FH * 2;
    float* sh_pre     = (float*)p;               p += (size_t)C * 256 * 4;
    float* sres       = (float*)p;               p += (size_t)C * 32 * 4;
    float* wts        = (float*)p;
    float* out        = (float*)d_out;

    hipLaunchKernelGGL(transpose_w_kernel, dim3(1536), dim3(256), 0, stream, w2, wg, wf, wt);
    hipLaunchKernelGGL(transpose_s_kernel, dim3(640), dim3(256), 0, stream, sw1, ssw, wcat);
    for (int c = 0; c < nChunks; ++c) {
        int tb = c * C;
        hipLaunchKernelGGL(grn_kernel, dim3(C / 32, 32), dim3(256), 0, stream,
                           x, w1, b1, b2, bg, bfp, gamma, beta, wsk, bsk,
                           wt, wt + 2097152, wt + 2 * 2097152, stacked, tb);
        hipLaunchKernelGGL(sel_gemm_kernel, dim3(C / 64), dim3(256), 0, stream,
                           stacked, wcat, sb1, ssb, sh_pre, sres);
        hipLaunchKernelGGL(sel_tail_kernel, dim3(C / 16), dim3(256), 0, stream,
                           sh_pre, sres, sw2, sb2, swg, sbg, swf, sbf, sgam, sbet, wts);
        hipLaunchKernelGGL(wsum_kernel, dim3(C), dim3(256), 0, stream, stacked, wts, out, tb);
    }
}

// Round 3
// 2061.763 us; speedup vs baseline: 1.6510x; 1.6510x over previous
//
#include <hip/hip_runtime.h>
#include <hip/hip_bf16.h>
#include <hip/hip_fp16.h>

#define BT 16384
#define F 32
#define H 256
#define FH 8192

typedef _Float16 half8 __attribute__((ext_vector_type(8)));
typedef float float4v __attribute__((ext_vector_type(4)));

#define GLD_LDS(gsrc, ldst) \
    __builtin_amdgcn_global_load_lds( \
        (const __attribute__((address_space(1))) void*)(gsrc), \
        (__attribute__((address_space(3))) void*)(ldst), 16, 0, 0)

// ---------------------------------------------------------------------------
// Prep: transpose w2/wg/wf (F,H_contr,H_out) fp32 -> [f][n_out][h_contr] fp16
// ---------------------------------------------------------------------------
__global__ __launch_bounds__(256) void transpose_w_kernel(
    const float* __restrict__ w2, const float* __restrict__ wg,
    const float* __restrict__ wf, _Float16* __restrict__ wt)
{
    __shared__ float tile[64][65];
    int bid = blockIdx.x;
    int tens = bid >> 9, rem = bid & 511;
    int f = rem >> 4, tl = rem & 15;
    int hb = (tl >> 2) * 64, nb = (tl & 3) * 64;
    const float* src = (tens == 0 ? w2 : (tens == 1 ? wg : wf)) + f * 65536;
    _Float16* dst = wt + (size_t)tens * 2097152 + f * 65536;
    int lane = threadIdx.x & 63, w = threadIdx.x >> 6;
    for (int i = 0; i < 16; ++i) {
        int r = i * 4 + w;
        tile[r][lane] = src[(hb + r) * 256 + nb + lane];
    }
    __syncthreads();
    for (int i = 0; i < 16; ++i) {
        int c = i * 4 + w;
        dst[(nb + c) * 256 + hb + lane] = (_Float16)tile[lane][c];
    }
}

// ---------------------------------------------------------------------------
// Prep: Wcat[n][k] fp16, n<256 from sw1 (8192,256), n in [256,288) from ssw
// ---------------------------------------------------------------------------
__global__ __launch_bounds__(256) void transpose_s_kernel(
    const float* __restrict__ sw1, const float* __restrict__ ssw,
    _Float16* __restrict__ wcat)
{
    __shared__ float tile[64][65];
    int bid = blockIdx.x;
    int lane = threadIdx.x & 63, w = threadIdx.x >> 6;
    if (bid < 512) {
        int k0 = (bid >> 2) * 64, n0 = (bid & 3) * 64;
        for (int i = 0; i < 16; ++i) {
            int r = i * 4 + w;
            tile[r][lane] = sw1[(size_t)(k0 + r) * 256 + n0 + lane];
        }
        __syncthreads();
        for (int i = 0; i < 16; ++i) {
            int c = i * 4 + w;
            wcat[(size_t)(n0 + c) * FH + k0 + lane] = (_Float16)tile[lane][c];
        }
    } else {
        int k0 = (bid - 512) * 64;
        int t = threadIdx.x;
        for (int i = 0; i < 8; ++i) {
            int idx = t + i * 256;
            int r = idx >> 5, cc = idx & 31;
            tile[r][cc] = ssw[(size_t)(k0 + r) * 32 + cc];
        }
        __syncthreads();
        for (int i = 0; i < 8; ++i) {
            int idx = t + i * 256;
            int c = idx >> 6, rr = idx & 63;
            wcat[(size_t)(256 + c) * FH + k0 + rr] = (_Float16)tile[rr][c];
        }
    }
}

// ---------------------------------------------------------------------------
// grn gemm stage with global_load_lds + XOR swizzle.
// Bs layout: 256 rows x 64 fp16 (unpadded). Row n, LDS chunk-pos cp (16B units)
// holds source chunk c = cp ^ (n&7). Fragment read for k-chunk (4*ks+q) of row
// n reads cp = (4*ks+q) ^ (n&7).
// ---------------------------------------------------------------------------
__device__ __forceinline__ void gemm_stage(
    const _Float16* __restrict__ Bsrc,   // weight slice for this f: [n][k], k contig
    const _Float16* As, _Float16* Bs,
    int t, int wv, int ln, int q, float4v acc[2][4])
{
    for (int kc = 0; kc < 4; ++kc) {
        __syncthreads();
#pragma unroll
        for (int it = 0; it < 8; ++it) {
            int s = it * 256 + t;          // LDS slot (wave-contiguous)
            int n = s >> 3;
            int c = (s & 7) ^ (n & 7);     // source chunk (xor swizzle)
            GLD_LDS(Bsrc + n * 256 + kc * 64 + c * 8, Bs + s * 8);
        }
        __syncthreads();
        for (int ks = 0; ks < 2; ++ks) {
            int kb = kc * 64 + ks * 32 + q * 8;
            half8 a0 = *(const half8*)&As[(0 + ln) * 264 + kb];
            half8 a1 = *(const half8*)&As[(16 + ln) * 264 + kb];
#pragma unroll
            for (int nt = 0; nt < 4; ++nt) {
                int n = wv * 64 + nt * 16 + ln;
                int cp = (ks * 4 + q) ^ (n & 7);
                half8 b8 = *(const half8*)&Bs[n * 64 + cp * 8];
                acc[0][nt] = __builtin_amdgcn_mfma_f32_16x16x32_f16(a0, b8, acc[0][nt], 0, 0, 0);
                acc[1][nt] = __builtin_amdgcn_mfma_f32_16x16x32_f16(a1, b8, acc[1][nt], 0, 0, 0);
            }
        }
    }
}

// ---------------------------------------------------------------------------
// Fused per-feature GRN: 3 GEMMs (K=256) + GLU + residual + LayerNorm
// One block = 32 tokens x one feature f. stacked written fp16 (chunk-local).
// f==0 blocks also initialize sh_pre/sres with biases (for splitk atomics).
// ---------------------------------------------------------------------------
__global__ __launch_bounds__(256) void grn_kernel(
    const float* __restrict__ x, const float* __restrict__ w1, const float* __restrict__ b1,
    const float* __restrict__ b2, const float* __restrict__ bg, const float* __restrict__ bfv_,
    const float* __restrict__ gamma, const float* __restrict__ beta,
    const float* __restrict__ wsk, const float* __restrict__ bsk,
    const _Float16* __restrict__ w2t, const _Float16* __restrict__ wgt,
    const _Float16* __restrict__ wft, _Float16* __restrict__ stacked,
    const float* __restrict__ sb1, const float* __restrict__ ssb,
    float* __restrict__ sh_pre, float* __restrict__ sres, int tok_base)
{
    __shared__ __align__(16) char smem[53248];
    _Float16* As = (_Float16*)smem;                     // 32 x 264 fp16
    float* xs = (float*)(smem + 16896);                 // 32
    _Float16* Bs = (_Float16*)(smem + 17024);           // 256 x 64 fp16 (swizzled)
    float* ys = (float*)(smem + 17024);                 // 32 x 265 f32 (alias Bs)
    float* red = (float*)(smem + 17024 + 33920);        // 512
    float* mv = (float*)(smem + 17024 + 33920 + 2048);  // 64

    const int f = blockIdx.y;
    const int tok0 = blockIdx.x * 32;                   // chunk-local
    const int t = threadIdx.x;
    const int wv = t >> 6;
    const int ln = t & 15;
    const int q = (t & 63) >> 4;

    // init splitk accumulators with biases (one f-slice of blocks does it)
    if (f == 0) {
        for (int i = t; i < 32 * 256; i += 256)
            sh_pre[(size_t)(tok0 + (i >> 8)) * 256 + (i & 255)] = sb1[i & 255];
        for (int i = t; i < 32 * 32; i += 256)
            sres[(size_t)(tok0 + (i >> 5)) * 32 + (i & 31)] = ssb[i & 31];
    }

    if (t < 32) xs[t] = x[(size_t)(tok_base + tok0 + t) * F + f];
    __syncthreads();

    // A = elu(x * w1 + b1), fp16 into LDS (32 x 256, stride 264)
    {
        float w1v = w1[f * H + t];
        float b1v = b1[f * H + t];
#pragma unroll 4
        for (int i = 0; i < 32; ++i) {
            float z = xs[i] * w1v + b1v;
            float e = z > 0.f ? z : (expf(z) - 1.f);
            As[i * 264 + t] = (_Float16)e;
        }
    }
    // stage 1: h2 = A @ w2 + b2
    float4v acc1[2][4];
#pragma unroll
    for (int mt = 0; mt < 2; ++mt)
#pragma unroll
        for (int nt = 0; nt < 4; ++nt)
#pragma unroll
            for (int r = 0; r < 4; ++r) acc1[mt][nt][r] = 0.f;
    gemm_stage(w2t + (size_t)f * 65536, As, Bs, t, wv, ln, q, acc1);

    __syncthreads();  // all stage-1 MFMA reads of As done
    {
        const float* b2f = b2 + f * H;
#pragma unroll
        for (int mt = 0; mt < 2; ++mt)
#pragma unroll
            for (int nt = 0; nt < 4; ++nt) {
                int n = wv * 64 + nt * 16 + ln;
                float b2v = b2f[n];
#pragma unroll
                for (int r = 0; r < 4; ++r) {
                    int m = mt * 16 + q * 4 + r;
                    As[m * 264 + n] = (_Float16)(acc1[mt][nt][r] + b2v);
                }
            }
    }
    // stage 2: Cg = h2 @ wg, Cf = h2 @ wf (sequential, reuse Bs)
    float4v accG[2][4], accF[2][4];
#pragma unroll
    for (int mt = 0; mt < 2; ++mt)
#pragma unroll
        for (int nt = 0; nt < 4; ++nt)
#pragma unroll
            for (int r = 0; r < 4; ++r) { accG[mt][nt][r] = 0.f; accF[mt][nt][r] = 0.f; }
    gemm_stage(wgt + (size_t)f * 65536, As, Bs, t, wv, ln, q, accG);
    gemm_stage(wft + (size_t)f * 65536, As, Bs, t, wv, ln, q, accF);

    // epilogue: y = sigmoid(Cg+bg)*(Cf+bf) + x*ws + bs, into LDS f32
    __syncthreads();
    {
        const float* bgf = bg + f * H;
        const float* bff = bfv_ + f * H;
        const float* wsf = wsk + f * H;
        const float* bsf = bsk + f * H;
#pragma unroll
        for (int mt = 0; mt < 2; ++mt)
#pragma unroll
            for (int nt = 0; nt < 4; ++nt) {
                int n = wv * 64 + nt * 16 + ln;
                float bgv = bgf[n], bfv = bff[n], wsv = wsf[n], bsv = bsf[n];
#pragma unroll
                for (int r = 0; r < 4; ++r) {
                    int m = mt * 16 + q * 4 + r;
                    float cg = accG[mt][nt][r] + bgv;
                    float cf = accF[mt][nt][r] + bfv;
                    float sig = 1.f / (1.f + expf(-cg));
                    ys[m * 265 + n] = sig * cf + xs[m] * wsv + bsv;
                }
            }
    }
    __syncthreads();
    // LayerNorm over H=256 per row
    {
        int row = t >> 3, seg = t & 7;
        float s1 = 0.f, s2 = 0.f;
#pragma unroll 8
        for (int j = 0; j < 32; ++j) {
            float v = ys[row * 265 + seg * 32 + j];
            s1 += v; s2 += v * v;
        }
        red[t] = s1; red[256 + t] = s2;
    }
    __syncthreads();
    if (t < 32) {
        float a = 0.f, b = 0.f;
        for (int s = 0; s < 8; ++s) { a += red[t * 8 + s]; b += red[256 + t * 8 + s]; }
        float mean = a * (1.f / 256.f);
        float var = b * (1.f / 256.f) - mean * mean;
        mv[t] = mean;
        mv[32 + t] = rsqrtf(var + 1e-5f);
    }
    __syncthreads();
    {
        float gv = gamma[f * H + t], bv = beta[f * H + t];
        for (int i = 0; i < 32; ++i) {
            float v = (ys[i * 265 + t] - mv[i]) * mv[32 + i] * gv + bv;
            stacked[(size_t)(tok0 + i) * FH + f * H + t] = (_Float16)v;
        }
    }
}

// ---------------------------------------------------------------------------
// Selection GEMM, split-K: grid (C/32 m-tiles, 8 k-slices). Each block:
// 32 tokens x N=288 x K=1024. Atomic fp32 add into sh_pre/sres (bias-inited).
// A/B tiles: unpadded 64-fp16 rows, xor-swizzled, global_load_lds staging.
// ---------------------------------------------------------------------------
__global__ __launch_bounds__(256) void sel_gemm_kernel(
    const _Float16* __restrict__ stacked, const _Float16* __restrict__ wcat,
    float* __restrict__ sh_pre, float* __restrict__ sres)
{
    __shared__ __align__(16) _Float16 As2[32 * 64];     // 4 KB
    __shared__ __align__(16) _Float16 Bs2[288 * 64];    // 36 KB
    const int t = threadIdx.x;
    const int wv = t >> 6, ln = t & 15, q = (t & 63) >> 4;
    const int tok0 = blockIdx.x * 32;                   // chunk-local
    const int kb = blockIdx.y;                          // k-slice 0..7
    const int NT = (wv < 2) ? 5 : 4;                    // n-tiles per wave (18 total)
    float4v acc[2][5];
#pragma unroll
    for (int mt = 0; mt < 2; ++mt)
#pragma unroll
        for (int i = 0; i < 5; ++i)
#pragma unroll
            for (int r = 0; r < 4; ++r) acc[mt][i][r] = 0.f;

    for (int kc = 0; kc < 16; ++kc) {
        const int k0 = (kb * 16 + kc) * 64;
        __syncthreads();
        {
            // A: 32 rows x 8 chunks = 256 slots (1/thread)
            int n = t >> 3;
            int c = (t & 7) ^ (n & 7);
            GLD_LDS(stacked + (size_t)(tok0 + n) * FH + k0 + c * 8, As2 + t * 8);
            // B: 288 rows x 8 chunks = 2304 slots (9/thread)
#pragma unroll
            for (int i = 0; i < 9; ++i) {
                int s = t + i * 256;
                int nb = s >> 3;
                int cb = (s & 7) ^ (nb & 7);
                GLD_LDS(wcat + (size_t)nb * FH + k0 + cb * 8, Bs2 + s * 8);
            }
        }
        __syncthreads();
        for (int ks = 0; ks < 2; ++ks) {
            half8 af[2];
#pragma unroll
            for (int mt = 0; mt < 2; ++mt) {
                int row = mt * 16 + ln;
                int cp = (ks * 4 + q) ^ (row & 7);
                af[mt] = *(const half8*)&As2[row * 64 + cp * 8];
            }
            for (int i = 0; i < NT; ++i) {
                int row = (wv + 4 * i) * 16 + ln;
                int cp = (ks * 4 + q) ^ (row & 7);
                half8 b8 = *(const half8*)&Bs2[row * 64 + cp * 8];
#pragma unroll
                for (int mt = 0; mt < 2; ++mt)
                    acc[mt][i] = __builtin_amdgcn_mfma_f32_16x16x32_f16(af[mt], b8, acc[mt][i], 0, 0, 0);
            }
        }
    }
    for (int i = 0; i < NT; ++i) {
        int n = (wv + 4 * i) * 16 + ln;
#pragma unroll
        for (int mt = 0; mt < 2; ++mt)
#pragma unroll
            for (int r = 0; r < 4; ++r) {
                int m = tok0 + mt * 16 + q * 4 + r;
                float v = acc[mt][i][r];
                if (n < 256) unsafeAtomicAdd(&sh_pre[(size_t)m * 256 + n], v);
                else         unsafeAtomicAdd(&sres[(size_t)m * 32 + (n - 256)], v);
            }
    }
}

// ---------------------------------------------------------------------------
// Fused selection tail + weighted sum. Block = 8 tokens (32 lanes each).
// elu -> fc2(256->32) -> GLU -> LN -> softmax -> out = sum_f stacked*w
// ---------------------------------------------------------------------------
__global__ __launch_bounds__(256) void tail_kernel(
    const float* __restrict__ sh_pre, const float* __restrict__ sres,
    const _Float16* __restrict__ stacked,
    const float* __restrict__ sw2, const float* __restrict__ sb2,
    const float* __restrict__ swg, const float* __restrict__ sbg,
    const float* __restrict__ swf, const float* __restrict__ sbf,
    const float* __restrict__ sgam, const float* __restrict__ sbet,
    float* __restrict__ out, int tok_base)
{
    __shared__ float sw2s[256 * 32];                    // 32 KB
    __shared__ float swgs[1024], swfs[1024];            // 8 KB
    __shared__ float shv[8][257];                       // 8 tokens x 256 (+pad)
    __shared__ float wls[8][33];
    const int t = threadIdx.x;
    for (int i = 0; i < 32; ++i) sw2s[t + i * 256] = sw2[t + i * 256];
    for (int i = 0; i < 4; ++i) {
        swgs[t + i * 256] = swg[t + i * 256];
        swfs[t + i * 256] = swf[t + i * 256];
    }
    // stage elu(sh_pre) for 8 tokens
    for (int i = 0; i < 8; ++i) {
        int idx = t + i * 256;
        int gg = idx >> 8, col = idx & 255;
        float z = sh_pre[(size_t)(blockIdx.x * 8 + gg) * 256 + col];
        shv[gg][col] = z > 0.f ? z : (expf(z) - 1.f);
    }
    __syncthreads();
    const int g = t >> 5;                               // token group 0..7
    const int j = t & 31;                               // feature index
    const int token = blockIdx.x * 8 + g;               // chunk-local
    // fc2: 256 -> 32
    float p = sb2[j];
    for (int k = 0; k < 256; ++k) p += shv[g][k] * sw2s[k * 32 + j];
    // GLU via width-32 shuffles
    float gacc = sbg[j], uacc = sbf[j];
#pragma unroll 8
    for (int i = 0; i < 32; ++i) {
        float tv = __shfl(p, i, 32);
        gacc += tv * swgs[i * 32 + j];
        uacc += tv * swfs[i * 32 + j];
    }
    float sig = 1.f / (1.f + expf(-gacc));
    float sv = sres[(size_t)token * 32 + j] + sig * uacc;
    // LayerNorm over 32 lanes
    float s1 = sv, s2 = sv * sv;
    for (int off = 16; off; off >>= 1) {
        s1 += __shfl_xor(s1, off, 32);
        s2 += __shfl_xor(s2, off, 32);
    }
    float mean = s1 * (1.f / 32.f);
    float var = s2 * (1.f / 32.f) - mean * mean;
    float v = (sv - mean) * rsqrtf(var + 1e-5f) * sgam[j] + sbet[j];
    // softmax over 32 lanes
    float mx = v;
    for (int off = 16; off; off >>= 1) mx = fmaxf(mx, __shfl_xor(mx, off, 32));
    float e = expf(v - mx);
    float ssum = e;
    for (int off = 16; off; off >>= 1) ssum += __shfl_xor(ssum, off, 32);
    wls[g][j] = e / ssum;
    __syncthreads();
    // weighted sum over features for the block's 8 tokens
    for (int tk = 0; tk < 8; ++tk) {
        const _Float16* sp = stacked + (size_t)(blockIdx.x * 8 + tk) * FH;
        float a = 0.f;
#pragma unroll
        for (int f = 0; f < 32; ++f) a += (float)sp[f * 256 + t] * wls[tk][f];
        out[(size_t)(tok_base + blockIdx.x * 8 + tk) * 256 + t] = a;
    }
}

// ---------------------------------------------------------------------------
extern "C" void kernel_launch(void* const* d_in, const int* in_sizes, int n_in,
                              void* d_out, int out_size, void* d_ws, size_t ws_size,
                              hipStream_t stream)
{
    (void)in_sizes; (void)n_in; (void)out_size;
    const float* x    = (const float*)d_in[0];
    const float* w1   = (const float*)d_in[1];
    const float* b1   = (const float*)d_in[2];
    const float* w2   = (const float*)d_in[3];
    const float* b2   = (const float*)d_in[4];
    const float* wg   = (const float*)d_in[5];
    const float* bg   = (const float*)d_in[6];
    const float* wf   = (const float*)d_in[7];
    const float* bfp  = (const float*)d_in[8];
    const float* gamma= (const float*)d_in[9];
    const float* beta = (const float*)d_in[10];
    const float* wsk  = (const float*)d_in[11];
    const float* bsk  = (const float*)d_in[12];
    const float* sw1  = (const float*)d_in[13];
    const float* sb1  = (const float*)d_in[14];
    const float* sw2  = (const float*)d_in[15];
    const float* sb2  = (const float*)d_in[16];
    const float* swg  = (const float*)d_in[17];
    const float* sbg  = (const float*)d_in[18];
    const float* swf  = (const float*)d_in[19];
    const float* sbf  = (const float*)d_in[20];
    const float* sgam = (const float*)d_in[21];
    const float* sbet = (const float*)d_in[22];
    const float* ssw  = (const float*)d_in[23];
    const float* ssb  = (const float*)d_in[24];

    // ---- workspace layout, chunk size adaptive to ws_size ----
    const size_t fixedB = 12582912 + 4718592;            // wt (12 MiB) + wcat (4.5 MiB)
    int C = BT;                                          // tokens per chunk
    while (C > 512) {
        size_t need = fixedB + (size_t)C * 17664;        // per-token scratch (upper bound)
        if (need <= ws_size) break;
        C >>= 1;
    }
    const int nChunks = BT / C;

    char* ws = (char*)d_ws;
    _Float16* wt      = (_Float16*)ws;                                   // 3 x 2M fp16
    _Float16* wcat    = (_Float16*)(ws + 12582912);                      // 288 x 8192 fp16
    char* p = ws + fixedB;
    _Float16* stacked = (_Float16*)p;            p += (size_t)C * FH * 2;
    float* sh_pre     = (float*)p;               p += (size_t)C * 256 * 4;
    float* sres       = (float*)p;
    float* out        = (float*)d_out;

    hipLaunchKernelGGL(transpose_w_kernel, dim3(1536), dim3(256), 0, stream, w2, wg, wf, wt);
    hipLaunchKernelGGL(transpose_s_kernel, dim3(640), dim3(256), 0, stream, sw1, ssw, wcat);
    for (int c = 0; c < nChunks; ++c) {
        int tb = c * C;
        hipLaunchKernelGGL(grn_kernel, dim3(C / 32, 32), dim3(256), 0, stream,
                           x, w1, b1, b2, bg, bfp, gamma, beta, wsk, bsk,
                           wt, wt + 2097152, wt + 2 * 2097152, stacked,
                           sb1, ssb, sh_pre, sres, tb);
        hipLaunchKernelGGL(sel_gemm_kernel, dim3(C / 32, 8), dim3(256), 0, stream,
                           stacked, wcat, sh_pre, sres);
        hipLaunchKernelGGL(tail_kernel, dim3(C / 8), dim3(256), 0, stream,
                           sh_pre, sres, stacked, sw2, sb2, swg, sbg, swf, sbf,
                           sgam, sbet, out, tb);
    }
}